// Round 4
// baseline (61.660 us; speedup 1.0000x reference)
//
#include <hip/hip_runtime.h>
#include <stdint.h>

#define B_   4
#define CIN  32
#define COUT 32
#define NN   81920
#define KK   10
#define NT   128          // n-tile per block (4 waves x 32)

typedef unsigned short ushort_t;
typedef __attribute__((ext_vector_type(8))) short bf16x8;
typedef __attribute__((ext_vector_type(4))) float f32x4;

// float -> bf16 bits, round-to-nearest-even
__device__ __host__ __forceinline__ ushort_t f2bf(float f) {
    union { float f; unsigned int u; } v; v.f = f;
    unsigned int r = (v.u + 0x7FFFu + ((v.u >> 16) & 1u)) >> 16;
    return (ushort_t)r;
}

// ---------- Kernel 1: transpose+convert input (B, C, N) f32 -> xb (B, N, C) bf16 ----------
__global__ __launch_bounds__(256) void k_transpose(const float* __restrict__ in,
                                                   ushort_t* __restrict__ xb) {
    __shared__ float tile[32][65];
    const int b   = blockIdx.y;
    const int n0  = blockIdx.x * 64;
    const int tid = threadIdx.x;

#pragma unroll
    for (int i = 0; i < 8; ++i) {
        const int c = i * 4 + (tid >> 6);
        const int n = tid & 63;
        tile[c][n] = in[((size_t)b * CIN + c) * NN + n0 + n];
    }
    __syncthreads();
#pragma unroll
    for (int i = 0; i < 4; ++i) {
        const int n  = i * 16 + (tid >> 4);
        const int cp = tid & 15;
        const unsigned int u0 = f2bf(tile[2 * cp][n]);
        const unsigned int u1 = f2bf(tile[2 * cp + 1][n]);
        *(unsigned int*)&xb[((size_t)b * NN + n0 + n) * CIN + 2 * cp] = u0 | (u1 << 16);
    }
}

// ---------- Kernel 2: gathered conv as MFMA GEMM, direct-to-VGPR B-fragments ----------
// out[b,o,n] = relu( sum_{ck} W[o,ck] * xb[b, tbl[k,n], c] + bias[o] )
// Lane (lr,lg)'s B-frag for mfma_16x16x32 is 16 CONTIGUOUS bytes of xb ->
// plain per-lane global_load_dwordx4; no LDS staging, no k-loop barriers.
__global__ __launch_bounds__(256) void k_main(const ushort_t* __restrict__ xb,
                                              const float* __restrict__ w,
                                              const float* __restrict__ bias,
                                              const int* __restrict__ tbl,
                                              float* __restrict__ out) {
    __shared__ ushort_t Wl[COUT][328];        // [o][k*32+c], pad -> spread A-read banks

    const int tid = threadIdx.x;
    const int bid = blockIdx.x;
    const int b    = (bid & 7) >> 1;          // batch -> XCD pair (L2 locality)
    const int tile = (bid >> 3) * 2 + (bid & 1);
    const int n0   = tile * NT;

    // weight convert f32 -> bf16 into LDS (40 KB/block, L2-resident: free)
    for (int idx = tid; idx < COUT * CIN * KK; idx += 256) {
        const int o = idx / 320, ck = idx % 320;
        const int k = ck >> 5, c = ck & 31;
        Wl[o][ck] = f2bf(w[((size_t)o * CIN + c) * KK + k]);
    }

    const int lane = tid & 63;
    const int wid  = tid >> 6;
    const int wn   = wid * 32;
    const int lr   = lane & 15;
    const int lg   = lane >> 4;

    // the two output rows this lane's B-frags come from
    const int r0 = n0 + wn + lr;
    const int r1 = r0 + 16;

    // preload all table entries (coalesced 16-dword segments, 4-way broadcast)
    int t0[KK], t1[KK];
#pragma unroll
    for (int k = 0; k < KK; ++k) {
        t0[k] = tbl[(size_t)k * NN + r0];
        t1[k] = tbl[(size_t)k * NN + r1];
    }

    f32x4 acc[2][2];
#pragma unroll
    for (int m = 0; m < 2; ++m) {
        f32x4 bv;
#pragma unroll
        for (int r = 0; r < 4; ++r) bv[r] = bias[m * 16 + lg * 4 + r];
        acc[m][0] = bv; acc[m][1] = bv;
    }

    __syncthreads();   // Wl visible

    const ushort_t* xB = xb + (size_t)b * NN * CIN;

#pragma unroll
    for (int k = 0; k < KK; ++k) {
        const bf16x8 b0 = *(const bf16x8*)(xB + (size_t)t0[k] * CIN + lg * 8);
        const bf16x8 b1 = *(const bf16x8*)(xB + (size_t)t1[k] * CIN + lg * 8);
        const bf16x8 a0 = *(const bf16x8*)&Wl[lr][k * 32 + lg * 8];
        const bf16x8 a1 = *(const bf16x8*)&Wl[16 + lr][k * 32 + lg * 8];
        acc[0][0] = __builtin_amdgcn_mfma_f32_16x16x32_bf16(a0, b0, acc[0][0], 0, 0, 0);
        acc[1][0] = __builtin_amdgcn_mfma_f32_16x16x32_bf16(a1, b0, acc[1][0], 0, 0, 0);
        acc[0][1] = __builtin_amdgcn_mfma_f32_16x16x32_bf16(a0, b1, acc[0][1], 0, 0, 0);
        acc[1][1] = __builtin_amdgcn_mfma_f32_16x16x32_bf16(a1, b1, acc[1][1], 0, 0, 0);
    }

#pragma unroll
    for (int m = 0; m < 2; ++m)
#pragma unroll
        for (int nt = 0; nt < 2; ++nt)
#pragma unroll
            for (int r = 0; r < 4; ++r) {
                const int o = m * 16 + lg * 4 + r;
                const int n = n0 + wn + nt * 16 + lr;
                const float v = acc[m][nt][r];
                out[((size_t)(b * COUT + o)) * NN + n] = v > 0.f ? v : 0.f;
            }
}

extern "C" void kernel_launch(void* const* d_in, const int* in_sizes, int n_in,
                              void* d_out, int out_size, void* d_ws, size_t ws_size,
                              hipStream_t stream) {
    const float* inp  = (const float*)d_in[0];
    const float* w    = (const float*)d_in[1];
    const float* bias = (const float*)d_in[2];
    const int*   tbl  = (const int*)d_in[3];

    ushort_t* xb = (ushort_t*)d_ws;                              // 20.97 MB
    float* out = (float*)d_out;

    k_transpose<<<dim3(NN / 64, B_), 256, 0, stream>>>(inp, xb);
    k_main<<<B_ * (NN / NT), 256, 0, stream>>>(xb, w, bias, tbl, out);
}

// Round 5
// 61.372 us; speedup vs baseline: 1.0047x; 1.0047x over previous
//
#include <hip/hip_runtime.h>
#include <stdint.h>

#define B_   4
#define CIN  32
#define COUT 32
#define NN   81920
#define KK   10
#define NT   128          // n-tile per block (4 waves x 32)

typedef unsigned short ushort_t;
typedef __attribute__((ext_vector_type(8))) short bf16x8;
typedef __attribute__((ext_vector_type(4))) float f32x4;

// float -> bf16 bits, round-to-nearest-even
__device__ __host__ __forceinline__ ushort_t f2bf(float f) {
    union { float f; unsigned int u; } v; v.f = f;
    unsigned int r = (v.u + 0x7FFFu + ((v.u >> 16) & 1u)) >> 16;
    return (ushort_t)r;
}

// ---------- Kernel 1: transpose+convert input (B, C, N) f32 -> xb (B, N, C) bf16 ----------
__global__ __launch_bounds__(256) void k_transpose(const float* __restrict__ in,
                                                   ushort_t* __restrict__ xb) {
    __shared__ float tile[32][65];
    const int b   = blockIdx.y;
    const int n0  = blockIdx.x * 64;
    const int tid = threadIdx.x;

#pragma unroll
    for (int i = 0; i < 8; ++i) {
        const int c = i * 4 + (tid >> 6);
        const int n = tid & 63;
        tile[c][n] = in[((size_t)b * CIN + c) * NN + n0 + n];
    }
    __syncthreads();
#pragma unroll
    for (int i = 0; i < 4; ++i) {
        const int n  = i * 16 + (tid >> 4);
        const int cp = tid & 15;
        const unsigned int u0 = f2bf(tile[2 * cp][n]);
        const unsigned int u1 = f2bf(tile[2 * cp + 1][n]);
        *(unsigned int*)&xb[((size_t)b * NN + n0 + n) * CIN + 2 * cp] = u0 | (u1 << 16);
    }
}

// ---------- Kernel 2: gathered conv as MFMA GEMM, all-gathers-in-flight ----------
// out[b,o,n] = relu( sum_{ck} W[o,ck] * xb[b, tbl[k,n], c] + bias[o] )
// Phase 1 issues ALL 20 per-lane 16B gathers (80 VGPRs of B-frags in flight);
// phase 2 runs the MFMA chain with compiler-counted vmcnt waits.
__global__ __launch_bounds__(256, 4) void k_main(const ushort_t* __restrict__ xb,
                                                 const float* __restrict__ w,
                                                 const float* __restrict__ bias,
                                                 const int* __restrict__ tbl,
                                                 float* __restrict__ out) {
    __shared__ ushort_t Wl[COUT][328];        // [o][k*32+c], pad -> spread A-read banks

    const int tid = threadIdx.x;
    const int bid = blockIdx.x;
    const int b    = (bid & 7) >> 1;          // batch -> XCD pair (L2 locality)
    const int tile = (bid >> 3) * 2 + (bid & 1);
    const int n0   = tile * NT;

    // weight convert f32 -> bf16 into LDS (40 KB/block, L2-resident: free)
    for (int idx = tid; idx < COUT * CIN * KK; idx += 256) {
        const int o = idx / 320, ck = idx % 320;
        const int k = ck >> 5, c = ck & 31;
        Wl[o][ck] = f2bf(w[((size_t)o * CIN + c) * KK + k]);
    }

    const int lane = tid & 63;
    const int wid  = tid >> 6;
    const int wn   = wid * 32;
    const int lr   = lane & 15;
    const int lg   = lane >> 4;

    const int r0 = n0 + wn + lr;              // this lane's two B-frag rows
    const int r1 = r0 + 16;

    // table entries (coalesced 64B segments, 4-lane broadcast)
    int t0[KK], t1[KK];
#pragma unroll
    for (int k = 0; k < KK; ++k) {
        t0[k] = tbl[(size_t)k * NN + r0];
        t1[k] = tbl[(size_t)k * NN + r1];
    }

    __syncthreads();   // Wl visible; drains tbl loads too (cheap). Gathers go AFTER.

    const ushort_t* xB = xb + (size_t)b * NN * CIN;

    // ---- phase 1: issue all 20 gathers (static-indexed arrays -> registers) ----
    bf16x8 bf0[KK], bf1[KK];
#pragma unroll
    for (int k = 0; k < KK; ++k) {
        bf0[k] = *(const bf16x8*)(xB + (size_t)t0[k] * CIN + lg * 8);
        bf1[k] = *(const bf16x8*)(xB + (size_t)t1[k] * CIN + lg * 8);
    }

    // acc init overlaps gather latency
    f32x4 acc[2][2];
#pragma unroll
    for (int m = 0; m < 2; ++m) {
        f32x4 bv;
#pragma unroll
        for (int r = 0; r < 4; ++r) bv[r] = bias[m * 16 + lg * 4 + r];
        acc[m][0] = bv; acc[m][1] = bv;
    }

    // ---- phase 2: MFMA chain (A-frags from LDS, B-frags arrive per counted vmcnt) ----
#pragma unroll
    for (int k = 0; k < KK; ++k) {
        const bf16x8 a0 = *(const bf16x8*)&Wl[lr][k * 32 + lg * 8];
        const bf16x8 a1 = *(const bf16x8*)&Wl[16 + lr][k * 32 + lg * 8];
        acc[0][0] = __builtin_amdgcn_mfma_f32_16x16x32_bf16(a0, bf0[k], acc[0][0], 0, 0, 0);
        acc[1][0] = __builtin_amdgcn_mfma_f32_16x16x32_bf16(a1, bf0[k], acc[1][0], 0, 0, 0);
        acc[0][1] = __builtin_amdgcn_mfma_f32_16x16x32_bf16(a0, bf1[k], acc[0][1], 0, 0, 0);
        acc[1][1] = __builtin_amdgcn_mfma_f32_16x16x32_bf16(a1, bf1[k], acc[1][1], 0, 0, 0);
    }

#pragma unroll
    for (int m = 0; m < 2; ++m)
#pragma unroll
        for (int nt = 0; nt < 2; ++nt)
#pragma unroll
            for (int r = 0; r < 4; ++r) {
                const int o = m * 16 + lg * 4 + r;
                const int n = n0 + wn + nt * 16 + lr;
                const float v = acc[m][nt][r];
                out[((size_t)(b * COUT + o)) * NN + n] = v > 0.f ? v : 0.f;
            }
}

extern "C" void kernel_launch(void* const* d_in, const int* in_sizes, int n_in,
                              void* d_out, int out_size, void* d_ws, size_t ws_size,
                              hipStream_t stream) {
    const float* inp  = (const float*)d_in[0];
    const float* w    = (const float*)d_in[1];
    const float* bias = (const float*)d_in[2];
    const int*   tbl  = (const int*)d_in[3];

    ushort_t* xb = (ushort_t*)d_ws;                              // 20.97 MB
    float* out = (float*)d_out;

    k_transpose<<<dim3(NN / 64, B_), 256, 0, stream>>>(inp, xb);
    k_main<<<B_ * (NN / NT), 256, 0, stream>>>(xb, w, bias, tbl, out);
}